// Round 3
// baseline (642.621 us; speedup 1.0000x reference)
//
#include <hip/hip_runtime.h>
#include <hip/hip_cooperative_groups.h>

#define GN 4096
#define CAP 512
#define NGRAPH 64

namespace cg = cooperative_groups;

struct Params {
    const float *x, *adj; const int *batch;
    const float *W1, *b1, *a1w1, *a1b1, *a2w1, *a2b1;
    const float *W2, *b2, *a1w2, *a1b2, *a2w2, *a2b2;
    const float *W3, *b3, *a1w3, *a1b3, *a2w3, *a2b3;
    const float *Wf, *bf;
    float* out;
    int *cnt, *col;
    float *s1, *s2, *f, *h, *pbuf;
};

union SMem {
    struct { float As[16][66]; float Bs[16][68]; } lin;
    struct { float w[4][2][CAP]; int cols[4][CAP]; } attn;
    struct { int lcnt[4]; } scan;
    struct { int bnd[2]; float pooled2[2][192]; float pooled[192];
             float z[10]; float red[2]; } pool;
};

// ---------------- phase: CSR build (16 rows/block, 4 groups x 128) ----------
__device__ void scan_csr(SMem& sm, const float* __restrict__ adj,
                         int* __restrict__ cnt_, int* __restrict__ col_,
                         int b, int t)
{
    int sg = t >> 7, st = t & 127;
    for (int rr = 0; rr < 4; ++rr) {
        int r = b * 16 + rr * 4 + sg;
        if (st == 0) sm.scan.lcnt[sg] = 0;
        __syncthreads();
        const float* row = adj + (size_t)r * GN;
        int* cols = col_ + (size_t)r * CAP;
        for (int j = st * 4; j < GN; j += 512) {
            float4 v = *(const float4*)(row + j);
            if (v.x != 0.f) { int p = atomicAdd(&sm.scan.lcnt[sg], 1); if (p < CAP) cols[p] = j + 0; }
            if (v.y != 0.f) { int p = atomicAdd(&sm.scan.lcnt[sg], 1); if (p < CAP) cols[p] = j + 1; }
            if (v.z != 0.f) { int p = atomicAdd(&sm.scan.lcnt[sg], 1); if (p < CAP) cols[p] = j + 2; }
            if (v.w != 0.f) { int p = atomicAdd(&sm.scan.lcnt[sg], 1); if (p < CAP) cols[p] = j + 3; }
        }
        __syncthreads();
        if (st == 0) { int c = sm.scan.lcnt[sg]; cnt_[r] = c < CAP ? c : CAP; }
    }
}

// ------- phase: GEMM partials, 64x64 tile, K-split 4 across blocks ----------
// W layout [2][K][32]; col c -> head c>>5, feat c&31. pbuf[ks][row][64].
template<int K>
__device__ void linear_partial(SMem& sm, const float* __restrict__ A, int lda,
                               const float* __restrict__ W,
                               float* __restrict__ pbuf, int b, int t)
{
    const int KS = K / 4;
    int tile = b >> 2, ks = b & 3;
    int i0 = tile * 64;
    int tx = t & 15, ty = t >> 4;      // ty in [0,32): 2 rows each
    float acc[2][4] = {};
    for (int kc = ks * KS; kc < ks * KS + KS; kc += 16) {
        {   // stage A: 64 rows x 16 k, float2 per thread
            int m = t >> 3, kk2 = (t & 7) * 2;
            float2 a2 = *(const float2*)&A[(size_t)(i0 + m) * lda + kc + kk2];
            sm.lin.As[kk2][m] = a2.x;
            sm.lin.As[kk2 + 1][m] = a2.y;
        }
        {   // stage B: 16 k x 64 cols, float2 per thread
            int kk = t >> 5, c0 = (t & 31) * 2;
            const float* wp = W + (size_t)(c0 >> 5) * K * 32 + (size_t)(kc + kk) * 32 + (c0 & 31);
            float2 w2 = *(const float2*)wp;
            sm.lin.Bs[kk][c0] = w2.x; sm.lin.Bs[kk][c0 + 1] = w2.y;
        }
        __syncthreads();
#pragma unroll
        for (int kk = 0; kk < 16; ++kk) {
            float2 a2 = *(const float2*)&sm.lin.As[kk][ty * 2];
            float4 b4 = *(const float4*)&sm.lin.Bs[kk][tx * 4];
            float a[2] = {a2.x, a2.y};
            float bb[4] = {b4.x, b4.y, b4.z, b4.w};
#pragma unroll
            for (int i = 0; i < 2; ++i)
#pragma unroll
                for (int j = 0; j < 4; ++j) acc[i][j] += a[i] * bb[j];
        }
        __syncthreads();
    }
#pragma unroll
    for (int i = 0; i < 2; ++i) {
        int row = i0 + ty * 2 + i;
        float4 v = {acc[i][0], acc[i][1], acc[i][2], acc[i][3]};
        *(float4*)&pbuf[(size_t)ks * GN * 64 + (size_t)row * 64 + tx * 4] = v;
    }
}

// ------- phase: reduce partials + bias -> f, fused attention scores ---------
__device__ void reduce_scores(const float* __restrict__ pbuf,
                              const float* __restrict__ bias,
                              const float* __restrict__ a1w, const float* __restrict__ a1b,
                              const float* __restrict__ a2w, const float* __restrict__ a2b,
                              float* __restrict__ f, float* __restrict__ s1,
                              float* __restrict__ s2, int b, int t)
{
    int r = b * 16 + (t >> 5);
    int c0 = (t & 31) * 2;
    float vx = 0.f, vy = 0.f;
#pragma unroll
    for (int ks = 0; ks < 4; ++ks) {
        float2 p = *(const float2*)&pbuf[(size_t)ks * GN * 64 + (size_t)r * 64 + c0];
        vx += p.x; vy += p.y;
    }
    vx += bias[c0]; vy += bias[c0 + 1];
    float2 v = {vx, vy};
    *(float2*)&f[(size_t)r * 64 + c0] = v;
    float p1 = vx * a1w[c0] + vy * a1w[c0 + 1];
    float p2 = vx * a2w[c0] + vy * a2w[c0 + 1];
#pragma unroll
    for (int off = 1; off < 16; off <<= 1) {
        p1 += __shfl_xor(p1, off);
        p2 += __shfl_xor(p2, off);
    }
    if ((t & 15) == 0) {
        int head = (t >> 4) & 1;
        s1[head * GN + r] = p1 + a1b[head];
        s2[head * GN + r] = p2 + a2b[head];
    }
}

// ------- phase: sparse attention (16 rows/block, 4 groups x 2 waves) --------
__device__ void attn_layer(SMem& sm, const float* __restrict__ f,
                           const float* __restrict__ s1, const float* __restrict__ s2,
                           const int* __restrict__ cnt_, const int* __restrict__ col_,
                           float* __restrict__ xout, int ocol0, int b, int t)
{
    int g = t >> 7;          // group 0..3
    int k = (t >> 6) & 1;    // head (wave-aligned)
    int lane = t & 63;
    for (int rr = 0; rr < 4; ++rr) {
        int i = b * 16 + rr * 4 + g;
        int cnt = cnt_[i];
        const int* cols = col_ + (size_t)i * CAP;
        float s1i = s1[k * GN + i];
        float m = -1e30f;
        for (int c = lane; c < cnt; c += 64) {
            int j = cols[c];
            if (k == 0) sm.attn.cols[g][c] = j;
            float e = s1i + s2[k * GN + j];
            e = e > 0.f ? e : 0.01f * e;
            sm.attn.w[g][k][c] = e;
            m = fmaxf(m, e);
        }
#pragma unroll
        for (int off = 32; off; off >>= 1) m = fmaxf(m, __shfl_xor(m, off));
        float s = 0.f;
        for (int c = lane; c < cnt; c += 64) {
            float v = __expf(sm.attn.w[g][k][c] - m);
            sm.attn.w[g][k][c] = v;
            s += v;
        }
#pragma unroll
        for (int off = 32; off; off >>= 1) s += __shfl_xor(s, off);
        __syncthreads();
        int h = lane & 31, half = lane >> 5;
        float o = 0.f;
        for (int c = half; c < cnt; c += 2) {
            int j = sm.attn.cols[g][c];
            o += sm.attn.w[g][k][c] * f[(size_t)j * 64 + 32 * k + h];
        }
        o += __shfl_xor(o, 32);
        if (half == 0) {
            float v = o / s;
            xout[(size_t)i * 192 + ocol0 + 32 * k + h] = v > 0.f ? v : 0.f;
        }
        __syncthreads();
    }
}

// ------- phase: pooling + classifier (blocks 0..63) -------------------------
__device__ void pool_cls(SMem& sm, const float* __restrict__ hbuf,
                         const int* __restrict__ batch,
                         const float* __restrict__ Wf, const float* __restrict__ bfb,
                         float* __restrict__ out, int g, int t)
{
    if (t == 0) {
        int lo = 0, hi = GN;
        while (lo < hi) { int mid = (lo + hi) >> 1; if (batch[mid] < g) lo = mid + 1; else hi = mid; }
        sm.pool.bnd[0] = lo;
        hi = GN;
        while (lo < hi) { int mid = (lo + hi) >> 1; if (batch[mid] < g + 1) lo = mid + 1; else hi = mid; }
        sm.pool.bnd[1] = lo;
    }
    __syncthreads();
    int s = sm.pool.bnd[0], e = sm.pool.bnd[1];
    int col = t & 255, slice = t >> 8;
    float acc = 0.f;
    if (col < 192) {
        for (int n = s + slice; n < e; n += 2) acc += hbuf[(size_t)n * 192 + col];
        sm.pool.pooled2[slice][col] = acc;
    }
    __syncthreads();
    if (t < 192) {
        float tot = sm.pool.pooled2[0][t] + sm.pool.pooled2[1][t];
        sm.pool.pooled[t] = (e > s) ? tot / (float)(e - s) : 0.f;
    }
    __syncthreads();
    if (t < 10) {
        float zt = bfb[t];
        for (int c = 0; c < 192; ++c) zt += sm.pool.pooled[c] * Wf[c * 10 + t];
        sm.pool.z[t] = zt;
    }
    __syncthreads();
    if (t == 0) {
        float m = sm.pool.z[0];
        for (int o = 1; o < 10; ++o) m = fmaxf(m, sm.pool.z[o]);
        float ssum = 0.f;
        for (int o = 0; o < 10; ++o) ssum += __expf(sm.pool.z[o] - m);
        sm.pool.red[0] = m; sm.pool.red[1] = ssum;
    }
    __syncthreads();
    if (t < 10) out[g * 10 + t] = __expf(sm.pool.z[t] - sm.pool.red[0]) / sm.pool.red[1];
}

// ---------------- the cooperative megakernel --------------------------------
__global__ __launch_bounds__(512, 1) void mega(Params p)
{
    __shared__ SMem sm;
    cg::grid_group grid = cg::this_grid();
    int b = blockIdx.x, t = threadIdx.x;

    scan_csr(sm, p.adj, p.cnt, p.col, b, t);
    grid.sync();

    // layer 1
    linear_partial<512>(sm, p.x, 512, p.W1, p.pbuf, b, t);
    grid.sync();
    reduce_scores(p.pbuf, p.b1, p.a1w1, p.a1b1, p.a2w1, p.a2b1, p.f, p.s1, p.s2, b, t);
    grid.sync();
    attn_layer(sm, p.f, p.s1, p.s2, p.cnt, p.col, p.h, 0, b, t);
    grid.sync();

    // layer 2 (input: h[:,0:64])
    linear_partial<64>(sm, p.h, 192, p.W2, p.pbuf, b, t);
    grid.sync();
    reduce_scores(p.pbuf, p.b2, p.a1w2, p.a1b2, p.a2w2, p.a2b2, p.f, p.s1, p.s2, b, t);
    grid.sync();
    attn_layer(sm, p.f, p.s1, p.s2, p.cnt, p.col, p.h, 64, b, t);
    grid.sync();

    // layer 3 (input: h[:,64:128])
    linear_partial<64>(sm, p.h + 64, 192, p.W3, p.pbuf, b, t);
    grid.sync();
    reduce_scores(p.pbuf, p.b3, p.a1w3, p.a1b3, p.a2w3, p.a2b3, p.f, p.s1, p.s2, b, t);
    grid.sync();
    attn_layer(sm, p.f, p.s1, p.s2, p.cnt, p.col, p.h, 128, b, t);
    grid.sync();

    if (b < NGRAPH) pool_cls(sm, p.h, p.batch, p.Wf, p.bf, p.out, b, t);
}

extern "C" void kernel_launch(void* const* d_in, const int* in_sizes, int n_in,
                              void* d_out, int out_size, void* d_ws, size_t ws_size,
                              hipStream_t stream)
{
    Params p;
    p.x    = (const float*)d_in[0];
    p.adj  = (const float*)d_in[1];
    p.batch= (const int*)d_in[2];
    p.W1   = (const float*)d_in[3];  p.b1   = (const float*)d_in[4];
    p.a1w1 = (const float*)d_in[5];  p.a1b1 = (const float*)d_in[6];
    p.a2w1 = (const float*)d_in[7];  p.a2b1 = (const float*)d_in[8];
    p.W2   = (const float*)d_in[9];  p.b2   = (const float*)d_in[10];
    p.a1w2 = (const float*)d_in[11]; p.a1b2 = (const float*)d_in[12];
    p.a2w2 = (const float*)d_in[13]; p.a2b2 = (const float*)d_in[14];
    p.W3   = (const float*)d_in[15]; p.b3   = (const float*)d_in[16];
    p.a1w3 = (const float*)d_in[17]; p.a1b3 = (const float*)d_in[18];
    p.a2w3 = (const float*)d_in[19]; p.a2b3 = (const float*)d_in[20];
    p.Wf   = (const float*)d_in[21]; p.bf   = (const float*)d_in[22];
    p.out  = (float*)d_out;

    char* base = (char*)d_ws;
    p.cnt  = (int*)(base + 0);                 // 16 KiB
    p.s1   = (float*)(base + 16384);           // 32 KiB
    p.s2   = (float*)(base + 49152);           // 32 KiB
    p.f    = (float*)(base + 81920);           // 1 MiB
    p.h    = (float*)(base + 1130496);         // 3 MiB
    p.pbuf = (float*)(base + 4276224);         // 4 MiB
    p.col  = (int*)(base + 8470528);           // 8 MiB
    (void)ws_size; (void)n_in; (void)in_sizes; (void)out_size;

    void* args[] = { &p };
    hipLaunchCooperativeKernel((void*)mega, dim3(256), dim3(512), args, 0, stream);
}

// Round 4
// 248.405 us; speedup vs baseline: 2.5870x; 2.5870x over previous
//
#include <hip/hip_runtime.h>

#define GN 4096
#define CAP 512
#define NGRAPH 64

// ---------- CSR build: 1 block/row, ballot compaction, 1 atomic/wave-chunk --
__global__ __launch_bounds__(256) void build_csr(
    const float* __restrict__ adj, int* __restrict__ cnt_, int* __restrict__ col_)
{
    __shared__ int lcnt;
    int i = blockIdx.x, t = threadIdx.x;
    int wv = t >> 6, lane = t & 63;
    if (t == 0) lcnt = 0;
    __syncthreads();
    const float* row = adj + (size_t)i * GN;
    int* cols = col_ + (size_t)i * CAP;
    int wbase = wv * 1024;
#pragma unroll
    for (int q = 0; q < 4; ++q) {
        int j = wbase + q * 256 + lane * 4;           // contiguous 1KB per instr
        float4 v = *(const float4*)(row + j);
        int mask = (v.x != 0.f ? 1 : 0) | (v.y != 0.f ? 2 : 0)
                 | (v.z != 0.f ? 4 : 0) | (v.w != 0.f ? 8 : 0);
        int pc = __popc(mask);
        int scan = pc;
#pragma unroll
        for (int off = 1; off < 64; off <<= 1) {
            int nn = __shfl_up(scan, off);
            if (lane >= off) scan += nn;
        }
        int total = __shfl(scan, 63);
        int basew = 0;
        if (lane == 63 && total) basew = atomicAdd(&lcnt, total);
        basew = __shfl(basew, 63);
        int p = basew + scan - pc;
        while (mask) {
            int b = __ffs(mask) - 1;
            mask &= mask - 1;
            if (p < CAP) cols[p] = j + b;
            ++p;
        }
    }
    __syncthreads();
    if (t == 0) cnt_[i] = lcnt < CAP ? lcnt : CAP;
}

// ---------- layer-1 GEMM partials: 64x64 tile, K-split 4 -> 256 blocks ------
// W layout [2][K][32]; col c -> head c>>5, feat c&31. pbuf[ks][row][64].
template<int K>
__global__ __launch_bounds__(256) void linear_partial(
    const float* __restrict__ A, int lda, const float* __restrict__ W,
    float* __restrict__ pbuf)
{
    __shared__ float As[16][66];
    __shared__ float Bs[16][68];
    const int KS = K / 4;
    int tile = blockIdx.x >> 2, ks = blockIdx.x & 3;
    int i0 = tile * 64;
    int t = threadIdx.x, tx = t & 15, ty = t >> 4;
    float acc[4][4] = {};
    for (int kc = ks * KS; kc < ks * KS + KS; kc += 16) {
        {   // stage A: 64 rows x 16 k, float4 per thread
            int m = t >> 2, k4 = (t & 3) * 4;
            float4 a4 = *(const float4*)&A[(size_t)(i0 + m) * lda + kc + k4];
            As[k4 + 0][m] = a4.x; As[k4 + 1][m] = a4.y;
            As[k4 + 2][m] = a4.z; As[k4 + 3][m] = a4.w;
        }
        {   // stage B: 16 k x 64 cols, float4 per thread
            int kk = t >> 4, c0 = (t & 15) * 4;
            const float* wp = W + (size_t)(c0 >> 5) * K * 32
                                + (size_t)(kc + kk) * 32 + (c0 & 31);
            *(float4*)&Bs[kk][c0] = *(const float4*)wp;
        }
        __syncthreads();
#pragma unroll
        for (int kk = 0; kk < 16; ++kk) {
            float4 a4 = *(const float4*)&As[kk][ty * 4];
            float4 b4 = *(const float4*)&Bs[kk][tx * 4];
            float a[4] = {a4.x, a4.y, a4.z, a4.w};
            float b[4] = {b4.x, b4.y, b4.z, b4.w};
#pragma unroll
            for (int ii = 0; ii < 4; ++ii)
#pragma unroll
                for (int jj = 0; jj < 4; ++jj) acc[ii][jj] += a[ii] * b[jj];
        }
        __syncthreads();
    }
#pragma unroll
    for (int ii = 0; ii < 4; ++ii) {
        int r = i0 + ty * 4 + ii;
        float4 v = {acc[ii][0], acc[ii][1], acc[ii][2], acc[ii][3]};
        *(float4*)&pbuf[((size_t)ks * GN + r) * 64 + tx * 4] = v;
    }
}

// ---------- reduce partials + bias -> f, fused scores -----------------------
// s1 layout [2][GN]; s2i interleaved [GN][2].
__global__ __launch_bounds__(256) void reduce_scores(
    const float* __restrict__ pbuf, const float* __restrict__ bias,
    const float* __restrict__ a1w, const float* __restrict__ a1b,
    const float* __restrict__ a2w, const float* __restrict__ a2b,
    float* __restrict__ f, float* __restrict__ s1, float* __restrict__ s2i)
{
    int t = threadIdx.x;
    int r = blockIdx.x * 16 + (t >> 4);
    int c0 = (t & 15) * 4;
    float vx = 0.f, vy = 0.f, vz = 0.f, vw = 0.f;
#pragma unroll
    for (int ks = 0; ks < 4; ++ks) {
        float4 p = *(const float4*)&pbuf[((size_t)ks * GN + r) * 64 + c0];
        vx += p.x; vy += p.y; vz += p.z; vw += p.w;
    }
    float4 bi = *(const float4*)&bias[c0];
    vx += bi.x; vy += bi.y; vz += bi.z; vw += bi.w;
    float4 v = {vx, vy, vz, vw};
    *(float4*)&f[(size_t)r * 64 + c0] = v;
    float4 w1 = *(const float4*)&a1w[c0];
    float4 w2 = *(const float4*)&a2w[c0];
    float p1 = vx * w1.x + vy * w1.y + vz * w1.z + vw * w1.w;
    float p2 = vx * w2.x + vy * w2.y + vz * w2.z + vw * w2.w;
#pragma unroll
    for (int off = 1; off < 8; off <<= 1) {
        p1 += __shfl_xor(p1, off);
        p2 += __shfl_xor(p2, off);
    }
    if ((t & 7) == 0) {
        int head = (t >> 3) & 1;
        s1[head * GN + r] = p1 + a1b[head];
        s2i[r * 2 + head] = p2 + a2b[head];
    }
}

// ---------- layers 2/3: small-K linear + fused scores (64 blocks) -----------
template<int KDIM>
__global__ __launch_bounds__(256) void linear_scores(
    const float* __restrict__ A, int lda,
    const float* __restrict__ W, const float* __restrict__ bias,
    const float* __restrict__ a1w, const float* __restrict__ a1b,
    const float* __restrict__ a2w, const float* __restrict__ a2b,
    float* __restrict__ F, float* __restrict__ s1, float* __restrict__ s2i)
{
    __shared__ float As[16][68];
    __shared__ float Bs[16][68];
    int i0 = blockIdx.x * 64;
    int t = threadIdx.x;
    int tx = t & 15, ty = t >> 4;
    float acc[4][4] = {};
    for (int kc = 0; kc < KDIM; kc += 16) {
#pragma unroll
        for (int p = 0; p < 4; ++p) {
            int q = t + p * 256;
            int m = q >> 4, kk = q & 15;
            As[kk][m] = A[(size_t)(i0 + m) * lda + kc + kk];
        }
        {
            int kk = t >> 4, n0 = (t & 15) * 4;
            const float* wp = W + (size_t)(n0 >> 5) * KDIM * 32
                                + (size_t)(kc + kk) * 32 + (n0 & 31);
            *(float4*)&Bs[kk][n0] = *(const float4*)wp;
        }
        __syncthreads();
#pragma unroll
        for (int kk = 0; kk < 16; ++kk) {
            float4 a4 = *(const float4*)&As[kk][ty * 4];
            float4 b4 = *(const float4*)&Bs[kk][tx * 4];
            float a[4] = {a4.x, a4.y, a4.z, a4.w};
            float b[4] = {b4.x, b4.y, b4.z, b4.w};
#pragma unroll
            for (int i = 0; i < 4; ++i)
#pragma unroll
                for (int j = 0; j < 4; ++j) acc[i][j] += a[i] * b[j];
        }
        __syncthreads();
    }
    int col0 = tx * 4;
    float4 bi = *(const float4*)&bias[col0];
    float4 w1 = *(const float4*)&a1w[col0];
    float4 w2 = *(const float4*)&a2w[col0];
    int head = tx >> 3;
#pragma unroll
    for (int i = 0; i < 4; ++i) {
        int row = i0 + ty * 4 + i;
        float v0 = acc[i][0] + bi.x;
        float v1 = acc[i][1] + bi.y;
        float v2 = acc[i][2] + bi.z;
        float v3 = acc[i][3] + bi.w;
        float4 v4 = {v0, v1, v2, v3};
        *(float4*)&F[(size_t)row * 64 + col0] = v4;
        float p1 = v0 * w1.x + v1 * w1.y + v2 * w1.z + v3 * w1.w;
        float p2 = v0 * w2.x + v1 * w2.y + v2 * w2.z + v3 * w2.w;
#pragma unroll
        for (int off = 1; off < 8; off <<= 1) {
            p1 += __shfl_xor(p1, off);
            p2 += __shfl_xor(p2, off);
        }
        if ((tx & 7) == 0) {
            s1[head * GN + row] = p1 + a1b[head];
            s2i[row * 2 + head] = p2 + a2b[head];
        }
    }
}

// ---------- attention: 1 block/row, 4 waves, full-row gather per edge -------
__global__ __launch_bounds__(256) void attn_kernel(
    const float* __restrict__ f, const float* __restrict__ s1,
    const float* __restrict__ s2i, const int* __restrict__ cnt_,
    const int* __restrict__ col_, float* __restrict__ xout, int ocol0)
{
    __shared__ float w0[CAP], w1[CAP];
    __shared__ int colsS[CAP];
    __shared__ float red[4][4];
    __shared__ float part[4][64];
    int i = blockIdx.x, t = threadIdx.x;
    int wv = t >> 6, lane = t & 63;
    int cnt = cnt_[i];
    const int* cols = col_ + (size_t)i * CAP;
    float s10 = s1[i], s11 = s1[GN + i];
    float m0 = -1e30f, m1 = -1e30f;
    for (int c = t; c < cnt; c += 256) {
        int j = cols[c];
        colsS[c] = j;
        float2 s2v = *(const float2*)&s2i[j * 2];
        float e0 = s10 + s2v.x; e0 = e0 > 0.f ? e0 : 0.01f * e0;
        float e1 = s11 + s2v.y; e1 = e1 > 0.f ? e1 : 0.01f * e1;
        w0[c] = e0; w1[c] = e1;
        m0 = fmaxf(m0, e0); m1 = fmaxf(m1, e1);
    }
#pragma unroll
    for (int off = 32; off; off >>= 1) {
        m0 = fmaxf(m0, __shfl_xor(m0, off));
        m1 = fmaxf(m1, __shfl_xor(m1, off));
    }
    if (lane == 0) { red[wv][0] = m0; red[wv][1] = m1; }
    __syncthreads();
    m0 = fmaxf(fmaxf(red[0][0], red[1][0]), fmaxf(red[2][0], red[3][0]));
    m1 = fmaxf(fmaxf(red[0][1], red[1][1]), fmaxf(red[2][1], red[3][1]));
    float sum0 = 0.f, sum1 = 0.f;
    for (int c = t; c < cnt; c += 256) {
        float v0 = __expf(w0[c] - m0); w0[c] = v0; sum0 += v0;
        float v1 = __expf(w1[c] - m1); w1[c] = v1; sum1 += v1;
    }
#pragma unroll
    for (int off = 32; off; off >>= 1) {
        sum0 += __shfl_xor(sum0, off);
        sum1 += __shfl_xor(sum1, off);
    }
    if (lane == 0) { red[wv][2] = sum0; red[wv][3] = sum1; }
    __syncthreads();
    sum0 = red[0][2] + red[1][2] + red[2][2] + red[3][2];
    sum1 = red[0][3] + red[1][3] + red[2][3] + red[3][3];
    // phase B: wave per edge, full 64-col row gather (both heads at once)
    int head = lane >> 5;
    float o = 0.f;
    for (int c = wv; c < cnt; c += 4) {
        int j = colsS[c];
        float wgt = head ? w1[c] : w0[c];
        o += wgt * f[(size_t)j * 64 + lane];
    }
    part[wv][lane] = o;
    __syncthreads();
    if (wv == 0) {
        o = part[0][lane] + part[1][lane] + part[2][lane] + part[3][lane];
        float denom = head ? sum1 : sum0;
        float v = o / denom;
        xout[(size_t)i * 192 + ocol0 + lane] = v > 0.f ? v : 0.f;
    }
}

// ---------- fused pooling + classifier --------------------------------------
__global__ __launch_bounds__(192) void pool_classify(
    const float* __restrict__ hbuf, const int* __restrict__ batch,
    const float* __restrict__ Wf, const float* __restrict__ bfb,
    float* __restrict__ out)
{
    __shared__ int bnd[2];
    __shared__ float pooled[192];
    __shared__ float z[10];
    __shared__ float red[2];
    int g = blockIdx.x, t = threadIdx.x;
    if (t == 0) {
        int lo = 0, hi = GN;
        while (lo < hi) { int mid = (lo + hi) >> 1; if (batch[mid] < g) lo = mid + 1; else hi = mid; }
        bnd[0] = lo;
        hi = GN;
        while (lo < hi) { int mid = (lo + hi) >> 1; if (batch[mid] < g + 1) lo = mid + 1; else hi = mid; }
        bnd[1] = lo;
    }
    __syncthreads();
    int s = bnd[0], e = bnd[1];
    float acc = 0.f;
    for (int n = s; n < e; ++n) acc += hbuf[(size_t)n * 192 + t];
    pooled[t] = (e > s) ? acc / (float)(e - s) : 0.f;
    __syncthreads();
    if (t < 10) {
        float zt = bfb[t];
        for (int c = 0; c < 192; ++c) zt += pooled[c] * Wf[c * 10 + t];
        z[t] = zt;
    }
    __syncthreads();
    if (t == 0) {
        float m = z[0];
        for (int o = 1; o < 10; ++o) m = fmaxf(m, z[o]);
        float ssum = 0.f;
        for (int o = 0; o < 10; ++o) ssum += __expf(z[o] - m);
        red[0] = m; red[1] = ssum;
    }
    __syncthreads();
    if (t < 10) out[g * 10 + t] = __expf(z[t] - red[0]) / red[1];
}

extern "C" void kernel_launch(void* const* d_in, const int* in_sizes, int n_in,
                              void* d_out, int out_size, void* d_ws, size_t ws_size,
                              hipStream_t stream)
{
    const float* x    = (const float*)d_in[0];
    const float* adj  = (const float*)d_in[1];
    const int*   batch= (const int*)d_in[2];
    const float* W1   = (const float*)d_in[3];
    const float* b1   = (const float*)d_in[4];
    const float* a1w1 = (const float*)d_in[5];
    const float* a1b1 = (const float*)d_in[6];
    const float* a2w1 = (const float*)d_in[7];
    const float* a2b1 = (const float*)d_in[8];
    const float* W2   = (const float*)d_in[9];
    const float* b2   = (const float*)d_in[10];
    const float* a1w2 = (const float*)d_in[11];
    const float* a1b2 = (const float*)d_in[12];
    const float* a2w2 = (const float*)d_in[13];
    const float* a2b2 = (const float*)d_in[14];
    const float* W3   = (const float*)d_in[15];
    const float* b3   = (const float*)d_in[16];
    const float* a1w3 = (const float*)d_in[17];
    const float* a1b3 = (const float*)d_in[18];
    const float* a2w3 = (const float*)d_in[19];
    const float* a2b3 = (const float*)d_in[20];
    const float* Wf   = (const float*)d_in[21];
    const float* bf   = (const float*)d_in[22];
    float* out = (float*)d_out;

    char* base = (char*)d_ws;
    int*   csr_cnt = (int*)(base + 0);            // 16 KiB
    float* s1      = (float*)(base + 16384);      // 32 KiB
    float* s2i     = (float*)(base + 49152);      // 32 KiB
    float* fbuf    = (float*)(base + 81920);      // 1 MiB
    float* hbuf    = (float*)(base + 1130496);    // 3 MiB
    float* pbuf    = (float*)(base + 4276224);    // 4 MiB
    int*   csr_col = (int*)(base + 8470528);      // 8 MiB
    (void)ws_size; (void)n_in; (void)in_sizes; (void)out_size;

    build_csr<<<GN, 256, 0, stream>>>(adj, csr_cnt, csr_col);

    // layer 1: K-split GEMM across all CUs, then reduce+scores
    linear_partial<512><<<256, 256, 0, stream>>>(x, 512, W1, pbuf);
    reduce_scores<<<GN / 16, 256, 0, stream>>>(pbuf, b1, a1w1, a1b1, a2w1, a2b1,
                                               fbuf, s1, s2i);
    attn_kernel<<<GN, 256, 0, stream>>>(fbuf, s1, s2i, csr_cnt, csr_col, hbuf, 0);

    linear_scores<64><<<GN / 64, 256, 0, stream>>>(hbuf, 192, W2, b2, a1w2, a1b2,
                                                   a2w2, a2b2, fbuf, s1, s2i);
    attn_kernel<<<GN, 256, 0, stream>>>(fbuf, s1, s2i, csr_cnt, csr_col, hbuf, 64);

    linear_scores<64><<<GN / 64, 256, 0, stream>>>(hbuf + 64, 192, W3, b3, a1w3, a1b3,
                                                   a2w3, a2b3, fbuf, s1, s2i);
    attn_kernel<<<GN, 256, 0, stream>>>(fbuf, s1, s2i, csr_cnt, csr_col, hbuf, 128);

    pool_classify<<<NGRAPH, 192, 0, stream>>>(hbuf, batch, Wf, bf, out);
}

// Round 5
// 241.861 us; speedup vs baseline: 2.6570x; 1.0271x over previous
//
#include <hip/hip_runtime.h>

#define GN 4096
#define CAP 512
#define NGRAPH 64

// ---------- layer-1 GEMM partials: 64x64 tile, K-split 8 -> 512 blocks ------
// W layout [2][K][32]; col c -> head c>>5, feat c&31. pbuf[ks][row][64].
template<int K, int NSPLIT>
__global__ __launch_bounds__(256) void linear_partial(
    const float* __restrict__ A, int lda, const float* __restrict__ W,
    float* __restrict__ pbuf)
{
    __shared__ float As[16][66];
    __shared__ float Bs[16][68];
    const int KS = K / NSPLIT;
    int tile = blockIdx.x / NSPLIT, ks = blockIdx.x % NSPLIT;
    int i0 = tile * 64;
    int t = threadIdx.x, tx = t & 15, ty = t >> 4;
    float acc[4][4] = {};
    for (int kc = ks * KS; kc < ks * KS + KS; kc += 16) {
        {   // stage A: 64 rows x 16 k, float4 per thread
            int m = t >> 2, k4 = (t & 3) * 4;
            float4 a4 = *(const float4*)&A[(size_t)(i0 + m) * lda + kc + k4];
            As[k4 + 0][m] = a4.x; As[k4 + 1][m] = a4.y;
            As[k4 + 2][m] = a4.z; As[k4 + 3][m] = a4.w;
        }
        {   // stage B: 16 k x 64 cols, float4 per thread
            int kk = t >> 4, c0 = (t & 15) * 4;
            const float* wp = W + (size_t)(c0 >> 5) * K * 32
                                + (size_t)(kc + kk) * 32 + (c0 & 31);
            *(float4*)&Bs[kk][c0] = *(const float4*)wp;
        }
        __syncthreads();
#pragma unroll
        for (int kk = 0; kk < 16; ++kk) {
            float4 a4 = *(const float4*)&As[kk][ty * 4];
            float4 b4 = *(const float4*)&Bs[kk][tx * 4];
            float a[4] = {a4.x, a4.y, a4.z, a4.w};
            float b[4] = {b4.x, b4.y, b4.z, b4.w};
#pragma unroll
            for (int ii = 0; ii < 4; ++ii)
#pragma unroll
                for (int jj = 0; jj < 4; ++jj) acc[ii][jj] += a[ii] * b[jj];
        }
        __syncthreads();
    }
#pragma unroll
    for (int ii = 0; ii < 4; ++ii) {
        int r = i0 + ty * 4 + ii;
        float4 v = {acc[ii][0], acc[ii][1], acc[ii][2], acc[ii][3]};
        *(float4*)&pbuf[((size_t)ks * GN + r) * 64 + tx * 4] = v;
    }
}

// ---------- reduce partials + bias -> f, fused scores -----------------------
// s1 layout [2][GN]; s2i interleaved [GN][2].
template<int NSPLIT>
__global__ __launch_bounds__(256) void reduce_scores(
    const float* __restrict__ pbuf, const float* __restrict__ bias,
    const float* __restrict__ a1w, const float* __restrict__ a1b,
    const float* __restrict__ a2w, const float* __restrict__ a2b,
    float* __restrict__ f, float* __restrict__ s1, float* __restrict__ s2i)
{
    int t = threadIdx.x;
    int r = blockIdx.x * 16 + (t >> 4);
    int c0 = (t & 15) * 4;
    float vx = 0.f, vy = 0.f, vz = 0.f, vw = 0.f;
#pragma unroll
    for (int ks = 0; ks < NSPLIT; ++ks) {
        float4 p = *(const float4*)&pbuf[((size_t)ks * GN + r) * 64 + c0];
        vx += p.x; vy += p.y; vz += p.z; vw += p.w;
    }
    float4 bi = *(const float4*)&bias[c0];
    vx += bi.x; vy += bi.y; vz += bi.z; vw += bi.w;
    float4 v = {vx, vy, vz, vw};
    *(float4*)&f[(size_t)r * 64 + c0] = v;
    float4 w1 = *(const float4*)&a1w[c0];
    float4 w2 = *(const float4*)&a2w[c0];
    float p1 = vx * w1.x + vy * w1.y + vz * w1.z + vw * w1.w;
    float p2 = vx * w2.x + vy * w2.y + vz * w2.z + vw * w2.w;
#pragma unroll
    for (int off = 1; off < 8; off <<= 1) {
        p1 += __shfl_xor(p1, off);
        p2 += __shfl_xor(p2, off);
    }
    if ((t & 7) == 0) {
        int head = (t >> 3) & 1;
        s1[head * GN + r] = p1 + a1b[head];
        s2i[r * 2 + head] = p2 + a2b[head];
    }
}

// ---------- layers 2/3: small-K linear + fused scores (64 blocks) -----------
template<int KDIM>
__global__ __launch_bounds__(256) void linear_scores(
    const float* __restrict__ A, int lda,
    const float* __restrict__ W, const float* __restrict__ bias,
    const float* __restrict__ a1w, const float* __restrict__ a1b,
    const float* __restrict__ a2w, const float* __restrict__ a2b,
    float* __restrict__ F, float* __restrict__ s1, float* __restrict__ s2i)
{
    __shared__ float As[16][68];
    __shared__ float Bs[16][68];
    int i0 = blockIdx.x * 64;
    int t = threadIdx.x;
    int tx = t & 15, ty = t >> 4;
    float acc[4][4] = {};
    for (int kc = 0; kc < KDIM; kc += 16) {
#pragma unroll
        for (int p = 0; p < 4; ++p) {
            int q = t + p * 256;
            int m = q >> 4, kk = q & 15;
            As[kk][m] = A[(size_t)(i0 + m) * lda + kc + kk];
        }
        {
            int kk = t >> 4, n0 = (t & 15) * 4;
            const float* wp = W + (size_t)(n0 >> 5) * KDIM * 32
                                + (size_t)(kc + kk) * 32 + (n0 & 31);
            *(float4*)&Bs[kk][n0] = *(const float4*)wp;
        }
        __syncthreads();
#pragma unroll
        for (int kk = 0; kk < 16; ++kk) {
            float4 a4 = *(const float4*)&As[kk][ty * 4];
            float4 b4 = *(const float4*)&Bs[kk][tx * 4];
            float a[4] = {a4.x, a4.y, a4.z, a4.w};
            float b[4] = {b4.x, b4.y, b4.z, b4.w};
#pragma unroll
            for (int i = 0; i < 4; ++i)
#pragma unroll
                for (int j = 0; j < 4; ++j) acc[i][j] += a[i] * b[j];
        }
        __syncthreads();
    }
    int col0 = tx * 4;
    float4 bi = *(const float4*)&bias[col0];
    float4 w1 = *(const float4*)&a1w[col0];
    float4 w2 = *(const float4*)&a2w[col0];
    int head = tx >> 3;
#pragma unroll
    for (int i = 0; i < 4; ++i) {
        int row = i0 + ty * 4 + i;
        float v0 = acc[i][0] + bi.x;
        float v1 = acc[i][1] + bi.y;
        float v2 = acc[i][2] + bi.z;
        float v3 = acc[i][3] + bi.w;
        float4 v4 = {v0, v1, v2, v3};
        *(float4*)&F[(size_t)row * 64 + col0] = v4;
        float p1 = v0 * w1.x + v1 * w1.y + v2 * w1.z + v3 * w1.w;
        float p2 = v0 * w2.x + v1 * w2.y + v2 * w2.z + v3 * w2.w;
#pragma unroll
        for (int off = 1; off < 8; off <<= 1) {
            p1 += __shfl_xor(p1, off);
            p2 += __shfl_xor(p2, off);
        }
        if ((tx & 7) == 0) {
            s1[head * GN + row] = p1 + a1b[head];
            s2i[row * 2 + head] = p2 + a2b[head];
        }
    }
}

// ---------- shared attention body: edge list already in LDS -----------------
__device__ __forceinline__ void attn_body(
    int i, int t, int cnt, const int* colsS,         // colsS in LDS
    float* w0, float* w1, float red[4][4], float part[4][64],
    const float* __restrict__ f, const float* __restrict__ s1,
    const float* __restrict__ s2i, float* __restrict__ xout, int ocol0)
{
    int wv = t >> 6, lane = t & 63;
    float s10 = s1[i], s11 = s1[GN + i];
    float m0 = -1e30f, m1 = -1e30f;
    for (int c = t; c < cnt; c += 256) {
        int j = colsS[c];
        float2 s2v = *(const float2*)&s2i[j * 2];
        float e0 = s10 + s2v.x; e0 = e0 > 0.f ? e0 : 0.01f * e0;
        float e1 = s11 + s2v.y; e1 = e1 > 0.f ? e1 : 0.01f * e1;
        w0[c] = e0; w1[c] = e1;
        m0 = fmaxf(m0, e0); m1 = fmaxf(m1, e1);
    }
#pragma unroll
    for (int off = 32; off; off >>= 1) {
        m0 = fmaxf(m0, __shfl_xor(m0, off));
        m1 = fmaxf(m1, __shfl_xor(m1, off));
    }
    if (lane == 0) { red[wv][0] = m0; red[wv][1] = m1; }
    __syncthreads();
    m0 = fmaxf(fmaxf(red[0][0], red[1][0]), fmaxf(red[2][0], red[3][0]));
    m1 = fmaxf(fmaxf(red[0][1], red[1][1]), fmaxf(red[2][1], red[3][1]));
    float sum0 = 0.f, sum1 = 0.f;
    for (int c = t; c < cnt; c += 256) {
        float v0 = __expf(w0[c] - m0); w0[c] = v0; sum0 += v0;
        float v1 = __expf(w1[c] - m1); w1[c] = v1; sum1 += v1;
    }
#pragma unroll
    for (int off = 32; off; off >>= 1) {
        sum0 += __shfl_xor(sum0, off);
        sum1 += __shfl_xor(sum1, off);
    }
    if (lane == 0) { red[wv][2] = sum0; red[wv][3] = sum1; }
    __syncthreads();
    sum0 = red[0][2] + red[1][2] + red[2][2] + red[3][2];
    sum1 = red[0][3] + red[1][3] + red[2][3] + red[3][3];
    int head = lane >> 5;
    float o = 0.f;
    for (int c = wv; c < cnt; c += 4) {
        int j = colsS[c];
        float wgt = head ? w1[c] : w0[c];
        o += wgt * f[(size_t)j * 64 + lane];
    }
    part[wv][lane] = o;
    __syncthreads();
    if (wv == 0) {
        o = part[0][lane] + part[1][lane] + part[2][lane] + part[3][lane];
        float denom = head ? sum1 : sum0;
        float v = o / denom;
        xout[(size_t)i * 192 + ocol0 + lane] = v > 0.f ? v : 0.f;
    }
}

// ---------- layer-1 attention with fused adj-row scan + CSR write -----------
__global__ __launch_bounds__(256) void attn_csr_kernel(
    const float* __restrict__ adj, const float* __restrict__ f,
    const float* __restrict__ s1, const float* __restrict__ s2i,
    int* __restrict__ cnt_, int* __restrict__ col_,
    float* __restrict__ xout)
{
    __shared__ float w0[CAP], w1[CAP];
    __shared__ int colsS[CAP];
    __shared__ float red[4][4];
    __shared__ float part[4][64];
    __shared__ int lcnt;
    int i = blockIdx.x, t = threadIdx.x;
    int wv = t >> 6, lane = t & 63;
    if (t == 0) lcnt = 0;
    __syncthreads();
    const float* row = adj + (size_t)i * GN;
    int wbase = wv * 1024;
#pragma unroll
    for (int q = 0; q < 4; ++q) {
        int j = wbase + q * 256 + lane * 4;
        float4 v = *(const float4*)(row + j);
        int mask = (v.x != 0.f ? 1 : 0) | (v.y != 0.f ? 2 : 0)
                 | (v.z != 0.f ? 4 : 0) | (v.w != 0.f ? 8 : 0);
        int pc = __popc(mask);
        int scan = pc;
#pragma unroll
        for (int off = 1; off < 64; off <<= 1) {
            int nn = __shfl_up(scan, off);
            if (lane >= off) scan += nn;
        }
        int total = __shfl(scan, 63);
        int basew = 0;
        if (lane == 63 && total) basew = atomicAdd(&lcnt, total);
        basew = __shfl(basew, 63);
        int p = basew + scan - pc;
        while (mask) {
            int b = __ffs(mask) - 1;
            mask &= mask - 1;
            if (p < CAP) colsS[p] = j + b;
            ++p;
        }
    }
    __syncthreads();
    int cnt = lcnt < CAP ? lcnt : CAP;
    // persist CSR for layers 2/3
    if (t == 0) cnt_[i] = cnt;
    int* gcols = col_ + (size_t)i * CAP;
    for (int c = t; c < cnt; c += 256) gcols[c] = colsS[c];
    attn_body(i, t, cnt, colsS, w0, w1, red, part, f, s1, s2i, xout, 0);
}

// ---------- layers 2/3 attention: edge list from global ---------------------
__global__ __launch_bounds__(256) void attn_kernel(
    const float* __restrict__ f, const float* __restrict__ s1,
    const float* __restrict__ s2i, const int* __restrict__ cnt_,
    const int* __restrict__ col_, float* __restrict__ xout, int ocol0)
{
    __shared__ float w0[CAP], w1[CAP];
    __shared__ int colsS[CAP];
    __shared__ float red[4][4];
    __shared__ float part[4][64];
    int i = blockIdx.x, t = threadIdx.x;
    int cnt = cnt_[i];
    const int* cols = col_ + (size_t)i * CAP;
    for (int c = t; c < cnt; c += 256) colsS[c] = cols[c];
    __syncthreads();
    attn_body(i, t, cnt, colsS, w0, w1, red, part, f, s1, s2i, xout, ocol0);
}

// ---------- fused pooling + classifier --------------------------------------
__global__ __launch_bounds__(192) void pool_classify(
    const float* __restrict__ hbuf, const int* __restrict__ batch,
    const float* __restrict__ Wf, const float* __restrict__ bfb,
    float* __restrict__ out)
{
    __shared__ int bnd[2];
    __shared__ float pooled[192];
    __shared__ float z[10];
    __shared__ float red[2];
    int g = blockIdx.x, t = threadIdx.x;
    if (t == 0) {
        int lo = 0, hi = GN;
        while (lo < hi) { int mid = (lo + hi) >> 1; if (batch[mid] < g) lo = mid + 1; else hi = mid; }
        bnd[0] = lo;
        hi = GN;
        while (lo < hi) { int mid = (lo + hi) >> 1; if (batch[mid] < g + 1) lo = mid + 1; else hi = mid; }
        bnd[1] = lo;
    }
    __syncthreads();
    int s = bnd[0], e = bnd[1];
    float acc = 0.f;
    for (int n = s; n < e; ++n) acc += hbuf[(size_t)n * 192 + t];
    pooled[t] = (e > s) ? acc / (float)(e - s) : 0.f;
    __syncthreads();
    if (t < 10) {
        float zt = bfb[t];
        for (int c = 0; c < 192; ++c) zt += pooled[c] * Wf[c * 10 + t];
        z[t] = zt;
    }
    __syncthreads();
    if (t == 0) {
        float m = z[0];
        for (int o = 1; o < 10; ++o) m = fmaxf(m, z[o]);
        float ssum = 0.f;
        for (int o = 0; o < 10; ++o) ssum += __expf(z[o] - m);
        red[0] = m; red[1] = ssum;
    }
    __syncthreads();
    if (t < 10) out[g * 10 + t] = __expf(z[t] - red[0]) / red[1];
}

extern "C" void kernel_launch(void* const* d_in, const int* in_sizes, int n_in,
                              void* d_out, int out_size, void* d_ws, size_t ws_size,
                              hipStream_t stream)
{
    const float* x    = (const float*)d_in[0];
    const float* adj  = (const float*)d_in[1];
    const int*   batch= (const int*)d_in[2];
    const float* W1   = (const float*)d_in[3];
    const float* b1   = (const float*)d_in[4];
    const float* a1w1 = (const float*)d_in[5];
    const float* a1b1 = (const float*)d_in[6];
    const float* a2w1 = (const float*)d_in[7];
    const float* a2b1 = (const float*)d_in[8];
    const float* W2   = (const float*)d_in[9];
    const float* b2   = (const float*)d_in[10];
    const float* a1w2 = (const float*)d_in[11];
    const float* a1b2 = (const float*)d_in[12];
    const float* a2w2 = (const float*)d_in[13];
    const float* a2b2 = (const float*)d_in[14];
    const float* W3   = (const float*)d_in[15];
    const float* b3   = (const float*)d_in[16];
    const float* a1w3 = (const float*)d_in[17];
    const float* a1b3 = (const float*)d_in[18];
    const float* a2w3 = (const float*)d_in[19];
    const float* a2b3 = (const float*)d_in[20];
    const float* Wf   = (const float*)d_in[21];
    const float* bf   = (const float*)d_in[22];
    float* out = (float*)d_out;

    char* base = (char*)d_ws;
    int*   csr_cnt = (int*)(base + 0);            // 16 KiB
    float* s1      = (float*)(base + 16384);      // 32 KiB
    float* s2i     = (float*)(base + 49152);      // 32 KiB
    float* fbuf    = (float*)(base + 81920);      // 1 MiB
    float* hbuf    = (float*)(base + 1130496);    // 3 MiB
    float* pbuf    = (float*)(base + 4276224);    // 8 MiB (8 x 1 MiB partials)
    int*   csr_col = (int*)(base + 12664832);     // 8 MiB
    (void)ws_size; (void)n_in; (void)in_sizes; (void)out_size;

    // layer 1: K-split-8 GEMM across 512 blocks (2/CU), reduce+scores,
    //          attention fused with adj scan + CSR persist
    linear_partial<512, 8><<<512, 256, 0, stream>>>(x, 512, W1, pbuf);
    reduce_scores<8><<<GN / 16, 256, 0, stream>>>(pbuf, b1, a1w1, a1b1, a2w1, a2b1,
                                                  fbuf, s1, s2i);
    attn_csr_kernel<<<GN, 256, 0, stream>>>(adj, fbuf, s1, s2i, csr_cnt, csr_col, hbuf);

    linear_scores<64><<<GN / 64, 256, 0, stream>>>(hbuf, 192, W2, b2, a1w2, a1b2,
                                                   a2w2, a2b2, fbuf, s1, s2i);
    attn_kernel<<<GN, 256, 0, stream>>>(fbuf, s1, s2i, csr_cnt, csr_col, hbuf, 64);

    linear_scores<64><<<GN / 64, 256, 0, stream>>>(hbuf + 64, 192, W3, b3, a1w3, a1b3,
                                                   a2w3, a2b3, fbuf, s1, s2i);
    attn_kernel<<<GN, 256, 0, stream>>>(fbuf, s1, s2i, csr_cnt, csr_col, hbuf, 128);

    pool_classify<<<NGRAPH, 192, 0, stream>>>(hbuf, batch, Wf, bf, out);
}

// Round 6
// 224.808 us; speedup vs baseline: 2.8585x; 1.0759x over previous
//
#include <hip/hip_runtime.h>

#define GN 4096
#define CAP 512
#define NGRAPH 64

// ---------- layer-1 GEMM partials: 64x64 tile, K-split 8 -> 512 blocks ------
// W layout [2][K][32]; col c -> head c>>5, feat c&31. pbuf[ks][row][64].
template<int K, int NSPLIT>
__global__ __launch_bounds__(256) void linear_partial(
    const float* __restrict__ A, int lda, const float* __restrict__ W,
    float* __restrict__ pbuf)
{
    __shared__ float As[16][66];
    __shared__ float Bs[16][68];
    const int KS = K / NSPLIT;
    int tile = blockIdx.x / NSPLIT, ks = blockIdx.x % NSPLIT;
    int i0 = tile * 64;
    int t = threadIdx.x, tx = t & 15, ty = t >> 4;
    float acc[4][4] = {};
    for (int kc = ks * KS; kc < ks * KS + KS; kc += 16) {
        {   // stage A: 64 rows x 16 k, float4 per thread
            int m = t >> 2, k4 = (t & 3) * 4;
            float4 a4 = *(const float4*)&A[(size_t)(i0 + m) * lda + kc + k4];
            As[k4 + 0][m] = a4.x; As[k4 + 1][m] = a4.y;
            As[k4 + 2][m] = a4.z; As[k4 + 3][m] = a4.w;
        }
        {   // stage B: 16 k x 64 cols, float4 per thread
            int kk = t >> 4, c0 = (t & 15) * 4;
            const float* wp = W + (size_t)(c0 >> 5) * K * 32
                                + (size_t)(kc + kk) * 32 + (c0 & 31);
            *(float4*)&Bs[kk][c0] = *(const float4*)wp;
        }
        __syncthreads();
#pragma unroll
        for (int kk = 0; kk < 16; ++kk) {
            float4 a4 = *(const float4*)&As[kk][ty * 4];
            float4 b4 = *(const float4*)&Bs[kk][tx * 4];
            float a[4] = {a4.x, a4.y, a4.z, a4.w};
            float b[4] = {b4.x, b4.y, b4.z, b4.w};
#pragma unroll
            for (int ii = 0; ii < 4; ++ii)
#pragma unroll
                for (int jj = 0; jj < 4; ++jj) acc[ii][jj] += a[ii] * b[jj];
        }
        __syncthreads();
    }
#pragma unroll
    for (int ii = 0; ii < 4; ++ii) {
        int r = i0 + ty * 4 + ii;
        float4 v = {acc[ii][0], acc[ii][1], acc[ii][2], acc[ii][3]};
        *(float4*)&pbuf[((size_t)ks * GN + r) * 64 + tx * 4] = v;
    }
}

// ---------- reduce partials + bias -> f, fused scores -----------------------
// s1 layout [2][GN]; s2i interleaved [GN][2].
template<int NSPLIT>
__global__ __launch_bounds__(256) void reduce_scores(
    const float* __restrict__ pbuf, const float* __restrict__ bias,
    const float* __restrict__ a1w, const float* __restrict__ a1b,
    const float* __restrict__ a2w, const float* __restrict__ a2b,
    float* __restrict__ f, float* __restrict__ s1, float* __restrict__ s2i)
{
    int t = threadIdx.x;
    int r = blockIdx.x * 16 + (t >> 4);
    int c0 = (t & 15) * 4;
    float vx = 0.f, vy = 0.f, vz = 0.f, vw = 0.f;
#pragma unroll
    for (int ks = 0; ks < NSPLIT; ++ks) {
        float4 p = *(const float4*)&pbuf[((size_t)ks * GN + r) * 64 + c0];
        vx += p.x; vy += p.y; vz += p.z; vw += p.w;
    }
    float4 bi = *(const float4*)&bias[c0];
    vx += bi.x; vy += bi.y; vz += bi.z; vw += bi.w;
    float4 v = {vx, vy, vz, vw};
    *(float4*)&f[(size_t)r * 64 + c0] = v;
    float4 w1 = *(const float4*)&a1w[c0];
    float4 w2 = *(const float4*)&a2w[c0];
    float p1 = vx * w1.x + vy * w1.y + vz * w1.z + vw * w1.w;
    float p2 = vx * w2.x + vy * w2.y + vz * w2.z + vw * w2.w;
#pragma unroll
    for (int off = 1; off < 8; off <<= 1) {
        p1 += __shfl_xor(p1, off);
        p2 += __shfl_xor(p2, off);
    }
    if ((t & 7) == 0) {
        int head = (t >> 3) & 1;
        s1[head * GN + r] = p1 + a1b[head];
        s2i[r * 2 + head] = p2 + a2b[head];
    }
}

// ---------- layers 2/3: K=64 linear + fused scores, 16-row tiles ------------
// 256 blocks (full CU coverage), single LDS stage, one barrier.
// Thread map: tx = t&15 (4-col group), ty = t>>4 (row). acc = 1 row x 4 cols.
__global__ __launch_bounds__(256) void linear_scores16(
    const float* __restrict__ A, int lda,
    const float* __restrict__ W, const float* __restrict__ bias,
    const float* __restrict__ a1w, const float* __restrict__ a1b,
    const float* __restrict__ a2w, const float* __restrict__ a2b,
    float* __restrict__ F, float* __restrict__ s1, float* __restrict__ s2i)
{
    __shared__ float As[64][18];   // [k][row]
    __shared__ float Bs[64][68];   // [k][col]
    int i0 = blockIdx.x * 16;
    int t = threadIdx.x, tx = t & 15, ty = t >> 4;
    {   // stage A: 16 rows x 64 k, one float4 per thread
        int m = t >> 4, k4 = (t & 15) * 4;
        float4 a4 = *(const float4*)&A[(size_t)(i0 + m) * lda + k4];
        As[k4 + 0][m] = a4.x; As[k4 + 1][m] = a4.y;
        As[k4 + 2][m] = a4.z; As[k4 + 3][m] = a4.w;
    }
#pragma unroll
    for (int p = 0; p < 4; ++p) {   // stage B: 64 k x 64 cols
        int idx = t + p * 256;
        int kk = idx >> 4, c0 = (idx & 15) * 4;
        const float* wp = W + (size_t)(c0 >> 5) * 64 * 32
                            + (size_t)kk * 32 + (c0 & 31);
        *(float4*)&Bs[kk][c0] = *(const float4*)wp;
    }
    __syncthreads();
    float acc[4] = {};
#pragma unroll
    for (int k = 0; k < 64; ++k) {
        float a = As[k][ty];
        float4 b4 = *(const float4*)&Bs[k][tx * 4];
        acc[0] += a * b4.x; acc[1] += a * b4.y;
        acc[2] += a * b4.z; acc[3] += a * b4.w;
    }
    int col0 = tx * 4;
    int row = i0 + ty;
    float4 bi = *(const float4*)&bias[col0];
    float4 w1 = *(const float4*)&a1w[col0];
    float4 w2 = *(const float4*)&a2w[col0];
    float v0 = acc[0] + bi.x, v1 = acc[1] + bi.y;
    float v2 = acc[2] + bi.z, v3 = acc[3] + bi.w;
    float4 v4 = {v0, v1, v2, v3};
    *(float4*)&F[(size_t)row * 64 + col0] = v4;
    float p1 = v0 * w1.x + v1 * w1.y + v2 * w1.z + v3 * w1.w;
    float p2 = v0 * w2.x + v1 * w2.y + v2 * w2.z + v3 * w2.w;
#pragma unroll
    for (int off = 1; off < 8; off <<= 1) {
        p1 += __shfl_xor(p1, off);
        p2 += __shfl_xor(p2, off);
    }
    if ((tx & 7) == 0) {
        int head = tx >> 3;
        s1[head * GN + row] = p1 + a1b[head];
        s2i[row * 2 + head] = p2 + a2b[head];
    }
}

// ---------- shared attention body: edge list already in LDS -----------------
__device__ __forceinline__ void attn_body(
    int i, int t, int cnt, const int* colsS,         // colsS in LDS
    float* w0, float* w1, float red[4][4], float part[4][64],
    const float* __restrict__ f, const float* __restrict__ s1,
    const float* __restrict__ s2i, float* __restrict__ xout, int ocol0)
{
    int wv = t >> 6, lane = t & 63;
    float s10 = s1[i], s11 = s1[GN + i];
    float m0 = -1e30f, m1 = -1e30f;
    for (int c = t; c < cnt; c += 256) {
        int j = colsS[c];
        float2 s2v = *(const float2*)&s2i[j * 2];
        float e0 = s10 + s2v.x; e0 = e0 > 0.f ? e0 : 0.01f * e0;
        float e1 = s11 + s2v.y; e1 = e1 > 0.f ? e1 : 0.01f * e1;
        w0[c] = e0; w1[c] = e1;
        m0 = fmaxf(m0, e0); m1 = fmaxf(m1, e1);
    }
#pragma unroll
    for (int off = 32; off; off >>= 1) {
        m0 = fmaxf(m0, __shfl_xor(m0, off));
        m1 = fmaxf(m1, __shfl_xor(m1, off));
    }
    if (lane == 0) { red[wv][0] = m0; red[wv][1] = m1; }
    __syncthreads();
    m0 = fmaxf(fmaxf(red[0][0], red[1][0]), fmaxf(red[2][0], red[3][0]));
    m1 = fmaxf(fmaxf(red[0][1], red[1][1]), fmaxf(red[2][1], red[3][1]));
    float sum0 = 0.f, sum1 = 0.f;
    for (int c = t; c < cnt; c += 256) {
        float v0 = __expf(w0[c] - m0); w0[c] = v0; sum0 += v0;
        float v1 = __expf(w1[c] - m1); w1[c] = v1; sum1 += v1;
    }
#pragma unroll
    for (int off = 32; off; off >>= 1) {
        sum0 += __shfl_xor(sum0, off);
        sum1 += __shfl_xor(sum1, off);
    }
    if (lane == 0) { red[wv][2] = sum0; red[wv][3] = sum1; }
    __syncthreads();
    sum0 = red[0][2] + red[1][2] + red[2][2] + red[3][2];
    sum1 = red[0][3] + red[1][3] + red[2][3] + red[3][3];
    int head = lane >> 5;
    float o = 0.f;
    for (int c = wv; c < cnt; c += 4) {
        int j = colsS[c];
        float wgt = head ? w1[c] : w0[c];
        o += wgt * f[(size_t)j * 64 + lane];
    }
    part[wv][lane] = o;
    __syncthreads();
    if (wv == 0) {
        o = part[0][lane] + part[1][lane] + part[2][lane] + part[3][lane];
        float denom = head ? sum1 : sum0;
        float v = o / denom;
        xout[(size_t)i * 192 + ocol0 + lane] = v > 0.f ? v : 0.f;
    }
}

// ---------- layer-1 attention with fused adj-row scan + CSR write -----------
__global__ __launch_bounds__(256) void attn_csr_kernel(
    const float* __restrict__ adj, const float* __restrict__ f,
    const float* __restrict__ s1, const float* __restrict__ s2i,
    int* __restrict__ cnt_, int* __restrict__ col_,
    float* __restrict__ xout)
{
    __shared__ float w0[CAP], w1[CAP];
    __shared__ int colsS[CAP];
    __shared__ float red[4][4];
    __shared__ float part[4][64];
    __shared__ int lcnt;
    int i = blockIdx.x, t = threadIdx.x;
    int wv = t >> 6, lane = t & 63;
    if (t == 0) lcnt = 0;
    __syncthreads();
    const float* row = adj + (size_t)i * GN;
    int wbase = wv * 1024;
#pragma unroll
    for (int q = 0; q < 4; ++q) {
        int j = wbase + q * 256 + lane * 4;
        float4 v = *(const float4*)(row + j);
        int mask = (v.x != 0.f ? 1 : 0) | (v.y != 0.f ? 2 : 0)
                 | (v.z != 0.f ? 4 : 0) | (v.w != 0.f ? 8 : 0);
        int pc = __popc(mask);
        int scan = pc;
#pragma unroll
        for (int off = 1; off < 64; off <<= 1) {
            int nn = __shfl_up(scan, off);
            if (lane >= off) scan += nn;
        }
        int total = __shfl(scan, 63);
        int basew = 0;
        if (lane == 63 && total) basew = atomicAdd(&lcnt, total);
        basew = __shfl(basew, 63);
        int p = basew + scan - pc;
        while (mask) {
            int b = __ffs(mask) - 1;
            mask &= mask - 1;
            if (p < CAP) colsS[p] = j + b;
            ++p;
        }
    }
    __syncthreads();
    int cnt = lcnt < CAP ? lcnt : CAP;
    // persist CSR for layers 2/3
    if (t == 0) cnt_[i] = cnt;
    int* gcols = col_ + (size_t)i * CAP;
    for (int c = t; c < cnt; c += 256) gcols[c] = colsS[c];
    attn_body(i, t, cnt, colsS, w0, w1, red, part, f, s1, s2i, xout, 0);
}

// ---------- layers 2/3 attention: edge list from global ---------------------
__global__ __launch_bounds__(256) void attn_kernel(
    const float* __restrict__ f, const float* __restrict__ s1,
    const float* __restrict__ s2i, const int* __restrict__ cnt_,
    const int* __restrict__ col_, float* __restrict__ xout, int ocol0)
{
    __shared__ float w0[CAP], w1[CAP];
    __shared__ int colsS[CAP];
    __shared__ float red[4][4];
    __shared__ float part[4][64];
    int i = blockIdx.x, t = threadIdx.x;
    int cnt = cnt_[i];
    const int* cols = col_ + (size_t)i * CAP;
    for (int c = t; c < cnt; c += 256) colsS[c] = cols[c];
    __syncthreads();
    attn_body(i, t, cnt, colsS, w0, w1, red, part, f, s1, s2i, xout, ocol0);
}

// ---------- fused pooling + classifier --------------------------------------
__global__ __launch_bounds__(192) void pool_classify(
    const float* __restrict__ hbuf, const int* __restrict__ batch,
    const float* __restrict__ Wf, const float* __restrict__ bfb,
    float* __restrict__ out)
{
    __shared__ int bnd[2];
    __shared__ float pooled[192];
    __shared__ float z[10];
    __shared__ float red[2];
    int g = blockIdx.x, t = threadIdx.x;
    if (t == 0) {
        int lo = 0, hi = GN;
        while (lo < hi) { int mid = (lo + hi) >> 1; if (batch[mid] < g) lo = mid + 1; else hi = mid; }
        bnd[0] = lo;
        hi = GN;
        while (lo < hi) { int mid = (lo + hi) >> 1; if (batch[mid] < g + 1) lo = mid + 1; else hi = mid; }
        bnd[1] = lo;
    }
    __syncthreads();
    int s = bnd[0], e = bnd[1];
    // 4 independent partial sums to break the serial add chain
    float a0 = 0.f, a1 = 0.f, a2 = 0.f, a3 = 0.f;
    int n = s;
    for (; n + 3 < e; n += 4) {
        a0 += hbuf[(size_t)(n + 0) * 192 + t];
        a1 += hbuf[(size_t)(n + 1) * 192 + t];
        a2 += hbuf[(size_t)(n + 2) * 192 + t];
        a3 += hbuf[(size_t)(n + 3) * 192 + t];
    }
    for (; n < e; ++n) a0 += hbuf[(size_t)n * 192 + t];
    float acc = (a0 + a1) + (a2 + a3);
    pooled[t] = (e > s) ? acc / (float)(e - s) : 0.f;
    __syncthreads();
    if (t < 10) {
        float zt = bfb[t];
        for (int c = 0; c < 192; ++c) zt += pooled[c] * Wf[c * 10 + t];
        z[t] = zt;
    }
    __syncthreads();
    if (t == 0) {
        float m = z[0];
        for (int o = 1; o < 10; ++o) m = fmaxf(m, z[o]);
        float ssum = 0.f;
        for (int o = 0; o < 10; ++o) ssum += __expf(z[o] - m);
        red[0] = m; red[1] = ssum;
    }
    __syncthreads();
    if (t < 10) out[g * 10 + t] = __expf(z[t] - red[0]) / red[1];
}

extern "C" void kernel_launch(void* const* d_in, const int* in_sizes, int n_in,
                              void* d_out, int out_size, void* d_ws, size_t ws_size,
                              hipStream_t stream)
{
    const float* x    = (const float*)d_in[0];
    const float* adj  = (const float*)d_in[1];
    const int*   batch= (const int*)d_in[2];
    const float* W1   = (const float*)d_in[3];
    const float* b1   = (const float*)d_in[4];
    const float* a1w1 = (const float*)d_in[5];
    const float* a1b1 = (const float*)d_in[6];
    const float* a2w1 = (const float*)d_in[7];
    const float* a2b1 = (const float*)d_in[8];
    const float* W2   = (const float*)d_in[9];
    const float* b2   = (const float*)d_in[10];
    const float* a1w2 = (const float*)d_in[11];
    const float* a1b2 = (const float*)d_in[12];
    const float* a2w2 = (const float*)d_in[13];
    const float* a2b2 = (const float*)d_in[14];
    const float* W3   = (const float*)d_in[15];
    const float* b3   = (const float*)d_in[16];
    const float* a1w3 = (const float*)d_in[17];
    const float* a1b3 = (const float*)d_in[18];
    const float* a2w3 = (const float*)d_in[19];
    const float* a2b3 = (const float*)d_in[20];
    const float* Wf   = (const float*)d_in[21];
    const float* bf   = (const float*)d_in[22];
    float* out = (float*)d_out;

    char* base = (char*)d_ws;
    int*   csr_cnt = (int*)(base + 0);            // 16 KiB
    float* s1      = (float*)(base + 16384);      // 32 KiB
    float* s2i     = (float*)(base + 49152);      // 32 KiB
    float* fbuf    = (float*)(base + 81920);      // 1 MiB
    float* hbuf    = (float*)(base + 1130496);    // 3 MiB
    float* pbuf    = (float*)(base + 4276224);    // 8 MiB (8 x 1 MiB partials)
    int*   csr_col = (int*)(base + 12664832);     // 8 MiB
    (void)ws_size; (void)n_in; (void)in_sizes; (void)out_size;

    // layer 1: K-split-8 GEMM across 512 blocks (2/CU), reduce+scores,
    //          attention fused with adj scan + CSR persist
    linear_partial<512, 8><<<512, 256, 0, stream>>>(x, 512, W1, pbuf);
    reduce_scores<8><<<GN / 16, 256, 0, stream>>>(pbuf, b1, a1w1, a1b1, a2w1, a2b1,
                                                  fbuf, s1, s2i);
    attn_csr_kernel<<<GN, 256, 0, stream>>>(adj, fbuf, s1, s2i, csr_cnt, csr_col, hbuf);

    linear_scores16<<<GN / 16, 256, 0, stream>>>(hbuf, 192, W2, b2, a1w2, a1b2,
                                                 a2w2, a2b2, fbuf, s1, s2i);
    attn_kernel<<<GN, 256, 0, stream>>>(fbuf, s1, s2i, csr_cnt, csr_col, hbuf, 64);

    linear_scores16<<<GN / 16, 256, 0, stream>>>(hbuf + 64, 192, W3, b3, a1w3, a1b3,
                                                 a2w3, a2b3, fbuf, s1, s2i);
    attn_kernel<<<GN, 256, 0, stream>>>(fbuf, s1, s2i, csr_cnt, csr_col, hbuf, 128);

    pool_classify<<<NGRAPH, 192, 0, stream>>>(hbuf, batch, Wf, bf, out);
}